// Round 8
// baseline (913.091 us; speedup 1.0000x reference)
//
#include <hip/hip_runtime.h>
#include <hip/hip_bf16.h>

typedef __attribute__((ext_vector_type(8))) short short8v;
typedef __attribute__((ext_vector_type(4))) float f32x4;

#define N_EDGES 1000000
#define NROWS   (N_EDGES * 3)
#define NTILES  (NROWS / 16)   // 187500 exactly
#define XN_ELEMS (50000 * 3 * 32)

__device__ __forceinline__ unsigned short f2bf(float f) {
    unsigned u = __builtin_bit_cast(unsigned, f);
    u += 0x7fffu + ((u >> 16) & 1u);           // round-to-nearest-even
    return (unsigned short)(u >> 16);
}

// Mc rows 0..31: 0.5*M1+0.25*M2 (src part); rows 32..63: -0.5*M1+0.25*M2 (dst)
__global__ void build_mc(const float* __restrict__ M1, const float* __restrict__ M2,
                         unsigned short* __restrict__ mc) {
    int i = blockIdx.x * blockDim.x + threadIdx.x;
    if (i >= 64 * 32) return;
    int k = i >> 5;
    int f = i & 31;
    float v;
    if (k < 32) v =  0.5f * M1[k * 32 + f]        + 0.25f * M2[k * 32 + f];
    else        v = -0.5f * M1[(k - 32) * 32 + f] + 0.25f * M2[(k - 32) * 32 + f];
    mc[i] = f2bf(v);
}

typedef __attribute__((ext_vector_type(4))) unsigned short u16x4;

__global__ __launch_bounds__(256) void convert_xn(const float* __restrict__ xn,
                                                  unsigned short* __restrict__ xb) {
    const int n4 = XN_ELEMS / 4;
    int i = blockIdx.x * blockDim.x + threadIdx.x;
    const int stride = gridDim.x * blockDim.x;
    for (; i < n4; i += stride) {
        f32x4 v = __builtin_nontemporal_load((const f32x4*)xn + i);
        u16x4 o;
        o[0] = f2bf(v.x); o[1] = f2bf(v.y); o[2] = f2bf(v.z); o[3] = f2bf(v.w);
        *((u16x4*)xb + i) = o;
    }
}

struct G4 { f32x4 w0, w1; short8v xs, xt; };

// MODE 0: real kernel. 1: no xb gather. 2: no W loads. 3: no stores.
// Modes 1-3 run the tile loop twice (visibility above harness fill dispatches).
template<int MODE>
__global__ __launch_bounds__(256) void n2e_tpl(
    const unsigned short* __restrict__ xb,
    const int*   __restrict__ src_idx,
    const int*   __restrict__ dst_idx,
    const float* __restrict__ W,
    const unsigned short* __restrict__ mc,
    float* __restrict__ out)
{
    const int lane = threadIdx.x & 63;
    const int wid  = threadIdx.x >> 6;
    const int col  = lane & 15;
    const int kg   = lane >> 4;
    const int kk   = kg << 3;

    short8v B00, B01, B10, B11;
    #pragma unroll
    for (int i = 0; i < 8; ++i) {
        int k0 = (kk + i) * 32;
        int k1 = (32 + kk + i) * 32;
        B00[i] = (short)mc[k0 + col];
        B01[i] = (short)mc[k0 + 16 + col];
        B10[i] = (short)mc[k1 + col];
        B11[i] = (short)mc[k1 + 16 + col];
    }

    const int NW = gridDim.x * 4;
    const int gw = blockIdx.x * 4 + wid;
    const int q  = NTILES / NW;
    const int rr = NTILES % NW;
    int t0, cnt;
    if (gw < rr) { cnt = q + 1; t0 = gw * cnt; }
    else         { cnt = q;     t0 = rr * (q + 1) + (gw - rr) * q; }
    if (cnt <= 0) return;
    const int tlast = t0 + cnt - 1;

    auto erow = [&](int T, int& e, int& d) {
        int row = (T << 4) + col;
        e = (int)((unsigned)row / 3u);
        d = row - e * 3;
    };
    auto ld_idx = [&](int T, int& s, int& t) {
        int e, d; erow(T, e, d);
        s = __builtin_nontemporal_load(src_idx + e);
        t = __builtin_nontemporal_load(dst_idx + e);
    };
    auto gather = [&](int T, int s, int t) -> G4 {
        int e, d; erow(T, e, d);
        G4 g;
        if constexpr (MODE != 2) {
            const float* wp = W + (size_t)e * 32 + kk;
            g.w0 = __builtin_nontemporal_load((const f32x4*)wp);
            g.w1 = __builtin_nontemporal_load((const f32x4*)(wp + 4));
        } else {
            g.w0 = f32x4{1.f, 1.f, 1.f, 1.f};
            g.w1 = f32x4{1.f, 1.f, 1.f, 1.f};
        }
        if constexpr (MODE != 1) {
            g.xs = *(const short8v*)(xb + ((size_t)s * 3 + d) * 32 + kk);
            g.xt = *(const short8v*)(xb + ((size_t)t * 3 + d) * 32 + kk);
        } else {
            asm volatile("" :: "v"(s), "v"(t));   // keep idx loads live
            short8v one;
            #pragma unroll
            for (int i = 0; i < 8; ++i) one[i] = (short)0x3f80;
            g.xs = one; g.xt = one;
        }
        return g;
    };

    const int reps = (MODE == 0) ? 1 : 2;
    for (int rep = 0; rep < reps; ++rep) {

        int T0 = t0;
        int T1 = (t0 + 1 <= tlast) ? t0 + 1 : tlast;
        int sA, tA, sB, tB;
        ld_idx(T0, sA, tA);
        ld_idx(T1, sB, tB);
        G4 gA = gather(T0, sA, tA);
        G4 gB = gather(T1, sB, tB);

        int sQ0, tQ0, sQ1, tQ1, sQ2, tQ2, sQ3, tQ3;
        { int T = (t0 + 2 <= tlast) ? t0 + 2 : tlast; ld_idx(T, sQ0, tQ0); }
        { int T = (t0 + 3 <= tlast) ? t0 + 3 : tlast; ld_idx(T, sQ1, tQ1); }
        { int T = (t0 + 4 <= tlast) ? t0 + 4 : tlast; ld_idx(T, sQ2, tQ2); }
        { int T = (t0 + 5 <= tlast) ? t0 + 5 : tlast; ld_idx(T, sQ3, tQ3); }

        for (int j = 0; j < cnt; ++j) {
            const int tc = t0 + j;

            int Tg = (tc + 2 <= tlast) ? tc + 2 : tlast;
            G4 gC = gather(Tg, sQ0, tQ0);

            int Ti = (tc + 6 <= tlast) ? tc + 6 : tlast;
            int sN, tN;
            ld_idx(Ti, sN, tN);

            __builtin_amdgcn_sched_barrier(0);

            float xsf[8], xtf[8];
            #pragma unroll
            for (int i = 0; i < 8; ++i) {
                xsf[i] = __builtin_bit_cast(float, ((unsigned)(unsigned short)gA.xs[i]) << 16);
                xtf[i] = __builtin_bit_cast(float, ((unsigned)(unsigned short)gA.xt[i]) << 16);
            }
            union { short8v v; __hip_bfloat162 h[4]; } ua, ub;
            ua.h[0] = __float22bfloat162_rn(make_float2(gA.w0.x * xsf[0], gA.w0.y * xsf[1]));
            ua.h[1] = __float22bfloat162_rn(make_float2(gA.w0.z * xsf[2], gA.w0.w * xsf[3]));
            ua.h[2] = __float22bfloat162_rn(make_float2(gA.w1.x * xsf[4], gA.w1.y * xsf[5]));
            ua.h[3] = __float22bfloat162_rn(make_float2(gA.w1.z * xsf[6], gA.w1.w * xsf[7]));
            ub.h[0] = __float22bfloat162_rn(make_float2(gA.w0.x * xtf[0], gA.w0.y * xtf[1]));
            ub.h[1] = __float22bfloat162_rn(make_float2(gA.w0.z * xtf[2], gA.w0.w * xtf[3]));
            ub.h[2] = __float22bfloat162_rn(make_float2(gA.w1.x * xtf[4], gA.w1.y * xtf[5]));
            ub.h[3] = __float22bfloat162_rn(make_float2(gA.w1.z * xtf[6], gA.w1.w * xtf[7]));

            f32x4 acc0 = {0.f, 0.f, 0.f, 0.f};
            f32x4 acc1 = {0.f, 0.f, 0.f, 0.f};
            acc0 = __builtin_amdgcn_mfma_f32_16x16x32_bf16(B00, ua.v, acc0, 0, 0, 0);
            acc0 = __builtin_amdgcn_mfma_f32_16x16x32_bf16(B10, ub.v, acc0, 0, 0, 0);
            acc1 = __builtin_amdgcn_mfma_f32_16x16x32_bf16(B01, ua.v, acc1, 0, 0, 0);
            acc1 = __builtin_amdgcn_mfma_f32_16x16x32_bf16(B11, ub.v, acc1, 0, 0, 0);

            if constexpr (MODE == 3) {
                asm volatile("" :: "v"(acc0[0]), "v"(acc0[1]), "v"(acc0[2]), "v"(acc0[3]),
                                   "v"(acc1[0]), "v"(acc1[1]), "v"(acc1[2]), "v"(acc1[3]));
            } else {
                float* op = out + (((size_t)((tc << 4) + col)) << 5) + (kg << 2);
                *(f32x4*)op        = acc0;
                *(f32x4*)(op + 16) = acc1;
            }

            gA = gB; gB = gC;
            sQ0 = sQ1; tQ0 = tQ1;
            sQ1 = sQ2; tQ1 = tQ2;
            sQ2 = sQ3; tQ2 = tQ3;
            sQ3 = sN;  tQ3 = tN;
        }
    }
}

extern "C" void kernel_launch(void* const* d_in, const int* in_sizes, int n_in,
                              void* d_out, int out_size, void* d_ws, size_t ws_size,
                              hipStream_t stream) {
    const float* xn  = (const float*)d_in[0];
    const int*   xs  = (const int*)  d_in[1];
    const int*   xd  = (const int*)  d_in[2];
    const float* W   = (const float*)d_in[3];
    const float* M1  = (const float*)d_in[4];
    const float* M2  = (const float*)d_in[5];
    float* out = (float*)d_out;

    unsigned short* mc = (unsigned short*)d_ws;                 // 4 KB
    unsigned short* xb = (unsigned short*)((char*)d_ws + 4096); // 9.6 MB

    hipLaunchKernelGGL(build_mc, dim3(8), dim3(256), 0, stream, M1, M2, mc);
    hipLaunchKernelGGL(convert_xn, dim3(1024), dim3(256), 0, stream, xn, xb);
    hipLaunchKernelGGL((n2e_tpl<0>), dim3(2048), dim3(256), 0, stream,
                       xb, xs, xd, W, mc, out);

    // ---- diagnostic ablations (separate dispatches; rocprof per-dispatch) ----
    hipLaunchKernelGGL((n2e_tpl<3>), dim3(2048), dim3(256), 0, stream,
                       xb, xs, xd, W, mc, out);   // out unused in mode 3
    if (ws_size >= ((size_t)32 << 20) + ((size_t)400 << 20)) {
        float* oscr = (float*)((char*)d_ws + ((size_t)32 << 20));
        hipLaunchKernelGGL((n2e_tpl<1>), dim3(2048), dim3(256), 0, stream,
                           xb, xs, xd, W, mc, oscr);
        hipLaunchKernelGGL((n2e_tpl<2>), dim3(2048), dim3(256), 0, stream,
                           xb, xs, xd, W, mc, oscr);
    }
}

// Round 9
// 210.069 us; speedup vs baseline: 4.3466x; 4.3466x over previous
//
#include <hip/hip_runtime.h>
#include <hip/hip_bf16.h>

typedef __attribute__((ext_vector_type(8))) short short8v;
typedef __attribute__((ext_vector_type(4))) float f32x4;

#define N_EDGES 1000000
#define NROWS   (N_EDGES * 3)
#define NTILES  (NROWS / 16)   // 187500 exactly
#define XN_ELEMS (50000 * 3 * 32)

__device__ __forceinline__ unsigned short f2bf(float f) {
    unsigned u = __builtin_bit_cast(unsigned, f);
    u += 0x7fffu + ((u >> 16) & 1u);           // round-to-nearest-even
    return (unsigned short)(u >> 16);
}

// Mc rows 0..31: 0.5*M1+0.25*M2 (src part); rows 32..63: -0.5*M1+0.25*M2 (dst)
__global__ void build_mc(const float* __restrict__ M1, const float* __restrict__ M2,
                         unsigned short* __restrict__ mc) {
    int i = blockIdx.x * blockDim.x + threadIdx.x;
    if (i >= 64 * 32) return;
    int k = i >> 5;
    int f = i & 31;
    float v;
    if (k < 32) v =  0.5f * M1[k * 32 + f]        + 0.25f * M2[k * 32 + f];
    else        v = -0.5f * M1[(k - 32) * 32 + f] + 0.25f * M2[(k - 32) * 32 + f];
    mc[i] = f2bf(v);
}

typedef __attribute__((ext_vector_type(4))) unsigned short u16x4;

__global__ __launch_bounds__(256) void convert_xn(const float* __restrict__ xn,
                                                  unsigned short* __restrict__ xb) {
    const int n4 = XN_ELEMS / 4;
    int i = blockIdx.x * blockDim.x + threadIdx.x;
    const int stride = gridDim.x * blockDim.x;
    for (; i < n4; i += stride) {
        f32x4 v = __builtin_nontemporal_load((const f32x4*)xn + i);
        u16x4 o;
        o[0] = f2bf(v.x); o[1] = f2bf(v.y); o[2] = f2bf(v.z); o[3] = f2bf(v.w);
        *((u16x4*)xb + i) = o;
    }
}

struct G4 { f32x4 w0, w1; short8v xs, xt; };

__global__ __launch_bounds__(256) void n2e_main(
    const unsigned short* __restrict__ xb,   // bf16 xn copy (ws)
    const int*   __restrict__ src_idx,
    const int*   __restrict__ dst_idx,
    const float* __restrict__ W,
    const unsigned short* __restrict__ mc,
    float* __restrict__ out)
{
    const int lane = threadIdx.x & 63;
    const int wid  = threadIdx.x >> 6;
    const int col  = lane & 15;        // edge-row within tile / D col
    const int kg   = lane >> 4;        // 0..3
    const int kk   = kg << 3;          // k-offset of this lane's 8 elements

    // Mc^T fragments (MFMA A operand): lane holds Mc[k=kk+i][half*16+col]
    short8v B00, B01, B10, B11;
    #pragma unroll
    for (int i = 0; i < 8; ++i) {
        int k0 = (kk + i) * 32;
        int k1 = (32 + kk + i) * 32;
        B00[i] = (short)mc[k0 + col];
        B01[i] = (short)mc[k0 + 16 + col];
        B10[i] = (short)mc[k1 + col];
        B11[i] = (short)mc[k1 + 16 + col];
    }

    // balanced contiguous chunk of tiles per wave
    const int NW = gridDim.x * 4;
    const int gw = blockIdx.x * 4 + wid;
    const int q  = NTILES / NW;
    const int rr = NTILES % NW;
    int t0, cnt;
    if (gw < rr) { cnt = q + 1; t0 = gw * cnt; }
    else         { cnt = q;     t0 = rr * (q + 1) + (gw - rr) * q; }
    if (cnt <= 0) return;
    const int tlast = t0 + cnt - 1;

    // helpers — ALL loads plain/cached (nt was the R3-R8 mistake: it bypassed
    // L2/L3, uncaching the idx/W streams -> over-fetch + 900-cyc latency)
    auto erow = [&](int T, int& e, int& d) {
        int row = (T << 4) + col;
        e = (int)((unsigned)row / 3u);
        d = row - e * 3;
    };
    auto ld_idx = [&](int T, int& s, int& t) {
        int e, d; erow(T, e, d);
        s = src_idx[e];
        t = dst_idx[e];
    };
    auto gather = [&](int T, int s, int t) -> G4 {
        int e, d; erow(T, e, d);
        G4 g;
        const float* wp = W + (size_t)e * 32 + kk;
        g.w0 = *(const f32x4*)wp;
        g.w1 = *(const f32x4*)(wp + 4);
        g.xs = *(const short8v*)(xb + ((size_t)s * 3 + d) * 32 + kk);
        g.xt = *(const short8v*)(xb + ((size_t)t * 3 + d) * 32 + kk);
        return g;
    };

    // ---- prologue -------------------------------------------------------
    int T0 = t0;
    int T1 = (t0 + 1 <= tlast) ? t0 + 1 : tlast;
    int sA, tA, sB, tB;
    ld_idx(T0, sA, tA);
    ld_idx(T1, sB, tB);
    G4 gA = gather(T0, sA, tA);
    G4 gB = gather(T1, sB, tB);

    // idx queue for tiles t+2 .. t+5
    int sQ0, tQ0, sQ1, tQ1, sQ2, tQ2, sQ3, tQ3;
    { int T = (t0 + 2 <= tlast) ? t0 + 2 : tlast; ld_idx(T, sQ0, tQ0); }
    { int T = (t0 + 3 <= tlast) ? t0 + 3 : tlast; ld_idx(T, sQ1, tQ1); }
    { int T = (t0 + 4 <= tlast) ? t0 + 4 : tlast; ld_idx(T, sQ2, tQ2); }
    { int T = (t0 + 5 <= tlast) ? t0 + 5 : tlast; ld_idx(T, sQ3, tQ3); }

    for (int j = 0; j < cnt; ++j) {
        const int tc = t0 + j;

        // ---- prefetch-issue section (pinned before compute) ----
        int Tg = (tc + 2 <= tlast) ? tc + 2 : tlast;
        G4 gC = gather(Tg, sQ0, tQ0);

        int Ti = (tc + 6 <= tlast) ? tc + 6 : tlast;
        int sN, tN;
        ld_idx(Ti, sN, tN);

        __builtin_amdgcn_sched_barrier(0);

        // ---- compute current tile from gA (loads 2 iterations old) ----
        float xsf[8], xtf[8];
        #pragma unroll
        for (int i = 0; i < 8; ++i) {
            xsf[i] = __builtin_bit_cast(float, ((unsigned)(unsigned short)gA.xs[i]) << 16);
            xtf[i] = __builtin_bit_cast(float, ((unsigned)(unsigned short)gA.xt[i]) << 16);
        }
        union { short8v v; __hip_bfloat162 h[4]; } ua, ub;
        ua.h[0] = __float22bfloat162_rn(make_float2(gA.w0.x * xsf[0], gA.w0.y * xsf[1]));
        ua.h[1] = __float22bfloat162_rn(make_float2(gA.w0.z * xsf[2], gA.w0.w * xsf[3]));
        ua.h[2] = __float22bfloat162_rn(make_float2(gA.w1.x * xsf[4], gA.w1.y * xsf[5]));
        ua.h[3] = __float22bfloat162_rn(make_float2(gA.w1.z * xsf[6], gA.w1.w * xsf[7]));
        ub.h[0] = __float22bfloat162_rn(make_float2(gA.w0.x * xtf[0], gA.w0.y * xtf[1]));
        ub.h[1] = __float22bfloat162_rn(make_float2(gA.w0.z * xtf[2], gA.w0.w * xtf[3]));
        ub.h[2] = __float22bfloat162_rn(make_float2(gA.w1.x * xtf[4], gA.w1.y * xtf[5]));
        ub.h[3] = __float22bfloat162_rn(make_float2(gA.w1.z * xtf[6], gA.w1.w * xtf[7]));

        // Transposed MFMA: D[m=f][n=edge-row]; A = Mc^T frags, B = edge data.
        f32x4 acc0 = {0.f, 0.f, 0.f, 0.f};   // f = kg*4+i
        f32x4 acc1 = {0.f, 0.f, 0.f, 0.f};   // f = kg*4+i + 16
        acc0 = __builtin_amdgcn_mfma_f32_16x16x32_bf16(B00, ua.v, acc0, 0, 0, 0);
        acc0 = __builtin_amdgcn_mfma_f32_16x16x32_bf16(B10, ub.v, acc0, 0, 0, 0);
        acc1 = __builtin_amdgcn_mfma_f32_16x16x32_bf16(B01, ua.v, acc1, 0, 0, 0);
        acc1 = __builtin_amdgcn_mfma_f32_16x16x32_bf16(B11, ub.v, acc1, 0, 0, 0);

        // lane stores 8 consecutive floats of one edge row — plain stores
        float* op = out + (((size_t)((tc << 4) + col)) << 5) + (kg << 2);
        *(f32x4*)op        = acc0;
        *(f32x4*)(op + 16) = acc1;

        // rotate pipeline registers
        gA = gB; gB = gC;
        sQ0 = sQ1; tQ0 = tQ1;
        sQ1 = sQ2; tQ1 = tQ2;
        sQ2 = sQ3; tQ2 = tQ3;
        sQ3 = sN;  tQ3 = tN;
    }
}

extern "C" void kernel_launch(void* const* d_in, const int* in_sizes, int n_in,
                              void* d_out, int out_size, void* d_ws, size_t ws_size,
                              hipStream_t stream) {
    const float* xn  = (const float*)d_in[0];
    const int*   xs  = (const int*)  d_in[1];
    const int*   xd  = (const int*)  d_in[2];
    const float* W   = (const float*)d_in[3];
    const float* M1  = (const float*)d_in[4];
    const float* M2  = (const float*)d_in[5];
    float* out = (float*)d_out;

    unsigned short* mc = (unsigned short*)d_ws;                 // 4 KB
    unsigned short* xb = (unsigned short*)((char*)d_ws + 4096); // 9.6 MB

    hipLaunchKernelGGL(build_mc, dim3(8), dim3(256), 0, stream, M1, M2, mc);
    hipLaunchKernelGGL(convert_xn, dim3(1024), dim3(256), 0, stream, xn, xb);
    hipLaunchKernelGGL(n2e_main, dim3(2048), dim3(256), 0, stream,
                       xb, xs, xd, W, mc, out);
}